// Round 9
// baseline (415.102 us; speedup 1.0000x reference)
//
#include <hip/hip_runtime.h>

#define HID 64
#define INDIM 128

typedef unsigned short ushort_t;
typedef unsigned int uint_t;

__device__ __forceinline__ float softplusf(float x) {
    return fmaxf(x, 0.f) + log1pf(expf(-fabsf(x)));
}
__device__ __forceinline__ ushort_t f2bf(float f) {
    union { float f; uint_t i; } c; c.f = f;
    uint_t u = c.i;
    u += 0x7FFFu + ((u >> 16) & 1u);   // round to nearest even
    return (ushort_t)(u >> 16);
}
__device__ __forceinline__ float lo_bf(uint_t u) {
    union { uint_t i; float f; } c; c.i = u << 16; return c.f;
}
__device__ __forceinline__ float hi_bf(uint_t u) {
    union { uint_t i; float f; } c; c.i = u & 0xFFFF0000u; return c.f;
}

// ------ H = x @ W (bf16 out) + zero cnt/smallb (grid covers N exactly) -----
__global__ __launch_bounds__(256) void k_gemm(const float* __restrict__ x,
                                              const float* __restrict__ W,
                                              ushort_t* __restrict__ Hb,
                                              int* __restrict__ cnt,
                                              float* __restrict__ smallb, int N) {
    __shared__ float Xs[64 * 132];
    __shared__ float Ws[128 * 64];
    int tid = threadIdx.x;
    int row0 = blockIdx.x * 64;

    if (tid < 64 && row0 + tid < N) cnt[row0 + tid] = 0;
    if (blockIdx.x == 0 && tid < 130) smallb[tid] = 0.f;

    const float4* W4 = (const float4*)W;
    float4* Ws4 = (float4*)Ws;
#pragma unroll
    for (int i = 0; i < 8; i++) Ws4[tid + 256 * i] = W4[tid + 256 * i];

#pragma unroll
    for (int i = 0; i < 8; i++) {
        int j = tid + 256 * i;
        int r = j >> 5, c4 = j & 31;
        int row = row0 + r;
        float4 v = make_float4(0.f, 0.f, 0.f, 0.f);
        if (row < N) v = *(const float4*)(x + row * INDIM + c4 * 4);
        *(float4*)(&Xs[r * 132 + c4 * 4]) = v;
    }
    __syncthreads();

    int tx = tid & 15;
    int ty = tid >> 4;
    float acc[4][4] = {};
    const float* xa = &Xs[(ty * 4) * 132];
#pragma unroll 4
    for (int k = 0; k < 128; k++) {
        float4 b = *(const float4*)(&Ws[k * 64 + tx * 4]);
#pragma unroll
        for (int i = 0; i < 4; i++) {
            float a = xa[i * 132 + k];
            acc[i][0] = fmaf(a, b.x, acc[i][0]);
            acc[i][1] = fmaf(a, b.y, acc[i][1]);
            acc[i][2] = fmaf(a, b.z, acc[i][2]);
            acc[i][3] = fmaf(a, b.w, acc[i][3]);
        }
    }
#pragma unroll
    for (int i = 0; i < 4; i++) {
        int row = row0 + ty * 4 + i;
        if (row < N) {
            ushort4 o;
            o.x = f2bf(acc[i][0]); o.y = f2bf(acc[i][1]);
            o.z = f2bf(acc[i][2]); o.w = f2bf(acc[i][3]);
            *(ushort4*)(&Hb[(size_t)row * HID + tx * 4]) = o;
        }
    }
}

// ------ fused: degree histogram + Hperm[n] = H[perm[n]] --------------------
// grid = (N*32 + 255)/256 threads: covers N*32 u32 copies; first E threads
// also do one histogram atomic each (E < N*32 here).
__global__ __launch_bounds__(256) void k_count_perm(const int* __restrict__ dst,
                                                    int* __restrict__ cnt, int E,
                                                    const int* __restrict__ perm,
                                                    const ushort_t* __restrict__ Hb,
                                                    ushort_t* __restrict__ Hpb, int N) {
    int g = blockIdx.x * 256 + threadIdx.x;
    if (g < E) atomicAdd(&cnt[dst[g]], 1);
    int total = N * 32;
    if (g < total) {
        int n = g >> 5, sub = g & 31;
        const uint_t* H32 = (const uint_t*)Hb;
        uint_t* Hp32 = (uint_t*)Hpb;
        Hp32[g] = H32[perm[n] * 32 + sub];
    }
}

// ---------------- scan stage 1: per-1024-chunk sums ------------------------
__global__ __launch_bounds__(256) void k_scan1(const int* __restrict__ cnt,
                                               int* __restrict__ partial, int N) {
    __shared__ int red[256];
    int base = blockIdx.x * 1024;
    int s = 0;
    for (int i = threadIdx.x; i < 1024; i += 256) {
        int idx = base + i;
        if (idx < N) s += cnt[idx];
    }
    red[threadIdx.x] = s;
    __syncthreads();
    for (int off = 128; off; off >>= 1) {
        if (threadIdx.x < off) red[threadIdx.x] += red[threadIdx.x + off];
        __syncthreads();
    }
    if (threadIdx.x == 0) partial[blockIdx.x] = red[0];
}

// ------ scan stage 2: redundant in-LDS scan of partials + per-chunk rowptr -
__global__ __launch_bounds__(256) void k_scan3(const int* __restrict__ cnt,
                                               const int* __restrict__ partial,
                                               int* __restrict__ rowptr,
                                               int* __restrict__ cursor,
                                               float* __restrict__ dinv,
                                               int N, int E) {
    __shared__ int sp[128];
    __shared__ int sc[256];
    int tid = threadIdx.x;
    int B98 = (N + 1023) >> 10;
    if (tid < 128) sp[tid] = (tid < B98) ? partial[tid] : 0;
    __syncthreads();
    for (int off = 1; off < 128; off <<= 1) {
        int v = (tid < 128 && tid >= off) ? sp[tid - off] : 0;
        __syncthreads();
        if (tid < 128) sp[tid] += v;
        __syncthreads();
    }
    int chunkEx = sp[blockIdx.x] - partial[blockIdx.x];
    __syncthreads();

    int base = blockIdx.x << 10;
    int i0 = base + tid * 4;
    int v0 = 0, v1 = 0, v2 = 0, v3 = 0;
    if (i0 + 3 < N) {
        int4 c = *(const int4*)(cnt + i0);
        v0 = c.x; v1 = c.y; v2 = c.z; v3 = c.w;
    } else {
        if (i0 < N)     v0 = cnt[i0];
        if (i0 + 1 < N) v1 = cnt[i0 + 1];
        if (i0 + 2 < N) v2 = cnt[i0 + 2];
        if (i0 + 3 < N) v3 = cnt[i0 + 3];
    }
    int s = v0 + v1 + v2 + v3;
    sc[tid] = s;
    __syncthreads();
    for (int off = 1; off < 256; off <<= 1) {
        int t = (tid >= off) ? sc[tid - off] : 0;
        __syncthreads();
        sc[tid] += t;
        __syncthreads();
    }
    int ex = sc[tid] - s + chunkEx;
    int r0 = ex, r1 = ex + v0, r2 = ex + v0 + v1, r3 = ex + v0 + v1 + v2;
    if (i0 < N)     { rowptr[i0]   = r0; cursor[i0]   = r0; dinv[i0]   = rsqrtf((float)(v0 + 1)); }
    if (i0 + 1 < N) { rowptr[i0+1] = r1; cursor[i0+1] = r1; dinv[i0+1] = rsqrtf((float)(v1 + 1)); }
    if (i0 + 2 < N) { rowptr[i0+2] = r2; cursor[i0+2] = r2; dinv[i0+2] = rsqrtf((float)(v2 + 1)); }
    if (i0 + 3 < N) { rowptr[i0+3] = r3; cursor[i0+3] = r3; dinv[i0+3] = rsqrtf((float)(v3 + 1)); }
    if (blockIdx.x == 0 && tid == 0) rowptr[N] = E;
}

// ------ bucket fill: csr[j] = src (4 B/edge — minimal scatter payload) -----
__global__ __launch_bounds__(256) void k_fill(const int* __restrict__ src,
                                              const int* __restrict__ dst,
                                              int* __restrict__ cursor,
                                              int* __restrict__ csr, int E) {
    int e = blockIdx.x * 256 + threadIdx.x;
    if (e >= E) return;
    int d = dst[e], s = src[e];
    int j = atomicAdd(&cursor[d], 1);
    csr[j] = s;
}

// ------ fused pull-gather: 2-deep pipelined csr+dinv prefetch --------------
__global__ __launch_bounds__(256) void k_gather(const ushort_t* __restrict__ Hb,
                                                const ushort_t* __restrict__ Hpb,
                                                const int* __restrict__ rowptr,
                                                const int* __restrict__ csr,
                                                const float* __restrict__ dinv,
                                                const float* __restrict__ b,
                                                const float* __restrict__ a,
                                                ushort_t* __restrict__ posb,
                                                ushort_t* __restrict__ negb,
                                                float* __restrict__ sumvec, int N) {
    int tid = threadIdx.x;
    int lane = tid & 63;
    int half = lane >> 5;
    int sub = lane & 31;
    int wid = (blockIdx.x * 256 + tid) >> 6;
    int nw = gridDim.x * 4;
    const uint_t* H32  = (const uint_t*)Hb;    // row stride = 32 u32
    const uint_t* Hp32 = (const uint_t*)Hpb;
    float2 b2 = ((const float2*)b)[sub];
    float2 a2 = ((const float2*)a)[sub];
    float sum0 = 0.f, sum1 = 0.f;

    for (int n = wid; n < N; n += nw) {
        float dv = dinv[n];
        float w2 = dv * dv;
        int beg = rowptr[n], end = rowptr[n + 1];
        float accP0 = 0.f, accP1 = 0.f, accN0 = 0.f, accN1 = 0.f;
        // pipeline prologue: quad0 indices+norms, quad1 indices
        int eA = beg + half, eB = beg + 2 + half;
        int sA0 = (eA < end) ? csr[eA] : 0;
        int sB0 = (eB < end) ? csr[eB] : 0;
        float nA0 = (eA < end) ? dinv[sA0] * dv : 0.f;
        float nB0 = (eB < end) ? dinv[sB0] * dv : 0.f;
        int sA1 = (eA + 4 < end) ? csr[eA + 4] : 0;
        int sB1 = (eB + 4 < end) ? csr[eB + 4] : 0;
        for (int j = beg; j < end; j += 4) {
            // prefetch quad j+8 indices (2 ahead)
            int sA2 = (eA + 8 < end) ? csr[eA + 8] : 0;
            int sB2 = (eB + 8 < end) ? csr[eB + 8] : 0;
            // norms for quad j+4 (indices loaded last iter; dinv is L2-hot)
            float nA1 = (eA + 4 < end) ? dinv[sA1] * dv : 0.f;
            float nB1 = (eB + 4 < end) ? dinv[sB1] * dv : 0.f;
            // gather current quad: pos from H, neg from Hperm (same index!)
            uint_t upA = H32[sA0 * 32 + sub];
            uint_t unA = Hp32[sA0 * 32 + sub];
            uint_t upB = H32[sB0 * 32 + sub];
            uint_t unB = Hp32[sB0 * 32 + sub];
            accP0 = fmaf(lo_bf(upA), nA0, accP0);
            accP1 = fmaf(hi_bf(upA), nA0, accP1);
            accN0 = fmaf(lo_bf(unA), nA0, accN0);
            accN1 = fmaf(hi_bf(unA), nA0, accN1);
            accP0 = fmaf(lo_bf(upB), nB0, accP0);
            accP1 = fmaf(hi_bf(upB), nB0, accP1);
            accN0 = fmaf(lo_bf(unB), nB0, accN0);
            accN1 = fmaf(hi_bf(unB), nB0, accN1);
            // rotate pipeline
            sA0 = sA1; sB0 = sB1; nA0 = nA1; nB0 = nB1;
            sA1 = sA2; sB1 = sB2;
            eA += 4; eB += 4;
        }
        accP0 += __shfl_xor(accP0, 32);
        accP1 += __shfl_xor(accP1, 32);
        accN0 += __shfl_xor(accN0, 32);
        accN1 += __shfl_xor(accN1, 32);
        // self-loop: pos half reads H[n], neg half reads Hperm[n] — both linear
        const uint_t* selfb = half ? Hp32 : H32;
        uint_t us = selfb[n * 32 + sub];
        float e0 = half ? accN0 : accP0;
        float e1 = half ? accN1 : accP1;
        float v0 = fmaf(lo_bf(us), w2, e0) + b2.x;
        float v1 = fmaf(hi_bf(us), w2, e1) + b2.y;
        v0 = v0 > 0.f ? v0 : v0 * a2.x;
        v1 = v1 > 0.f ? v1 : v1 * a2.y;
        uint_t packed = ((uint_t)f2bf(v1) << 16) | (uint_t)f2bf(v0);
        uint_t* outp = (uint_t*)(half ? negb : posb);
        outp[n * 32 + sub] = packed;
        if (!half) { sum0 += v0; sum1 += v1; }
    }

    __shared__ float red[4][64];
    int w = tid >> 6;
    if (!half) { red[w][2 * sub] = sum0; red[w][2 * sub + 1] = sum1; }
    __syncthreads();
    if (tid < 64) {
        float s = red[0][tid] + red[1][tid] + red[2][tid] + red[3][tid];
        atomicAdd(&sumvec[tid], s);
    }
}

// ------ loss with fused discriminator (svec computed per-block) ------------
__global__ __launch_bounds__(256) void k_loss(const ushort_t* __restrict__ posb,
                                              const ushort_t* __restrict__ negb,
                                              const float* __restrict__ sumvec,
                                              const float* __restrict__ Wd,
                                              float* __restrict__ lossAcc, int N) {
    __shared__ float summ[64];
    __shared__ float svecS[64];
    __shared__ float redL[8];
    int tid = threadIdx.x;
    if (tid < 64) summ[tid] = 1.f / (1.f + expf(-sumvec[tid] / (float)N));
    __syncthreads();
    if (tid < 64) {
        float s = 0.f;
#pragma unroll
        for (int j = 0; j < 64; j++) s += Wd[tid * 64 + j] * summ[j];
        svecS[tid] = s;
    }
    __syncthreads();

    int lane = tid & 63;
    int half = lane >> 5;
    int sub = lane & 31;
    int w = tid >> 6;
    float s0 = svecS[2 * sub], s1 = svecS[2 * sub + 1];
    const uint_t* P32 = (const uint_t*)(half ? negb : posb);
    float l = 0.f;
    int wid = (blockIdx.x * 256 + tid) >> 6;
    int nw = gridDim.x * 4;
    for (int n = wid; n < N; n += nw) {
        uint_t u = P32[n * 32 + sub];
        float p = lo_bf(u) * s0 + hi_bf(u) * s1;
        p += __shfl_xor(p, 1);
        p += __shfl_xor(p, 2);
        p += __shfl_xor(p, 4);
        p += __shfl_xor(p, 8);
        p += __shfl_xor(p, 16);
        if (sub == 0) l += half ? softplusf(p) : softplusf(-p);
    }
    if (sub == 0) redL[w * 2 + half] = l;
    __syncthreads();
    if (tid == 0) {
        float t = 0.f;
#pragma unroll
        for (int i = 0; i < 8; i++) t += redL[i];
        atomicAdd(&lossAcc[0], t);
    }
}

// ---------------- final scalar ---------------------------------------------
__global__ void k_final(const float* __restrict__ lossAcc, float* __restrict__ out, int N) {
    out[0] = lossAcc[0] / (float)N;
}

extern "C" void kernel_launch(void* const* d_in, const int* in_sizes, int n_in,
                              void* d_out, int out_size, void* d_ws, size_t ws_size,
                              hipStream_t stream) {
    const float* x      = (const float*)d_in[0];
    const float* W_gcn  = (const float*)d_in[1];
    const float* b_gcn  = (const float*)d_in[2];
    const float* prelu_a= (const float*)d_in[3];
    const float* W_disc = (const float*)d_in[4];
    const int*   eidx   = (const int*)d_in[5];
    const int*   perm   = (const int*)d_in[6];

    int N = in_sizes[0] / INDIM;      // 100000
    int E = in_sizes[5] / 2;          // 1600000
    const int* src = eidx;
    const int* dst = eidx + E;

    char* base = (char*)d_ws;
    size_t off = 0;
    auto alloc = [&](size_t bytes) { size_t o = off; off = (off + bytes + 255) & ~(size_t)255; return o; };
    ushort_t* Hb    = (ushort_t*)(base + alloc((size_t)N * HID * 2));
    ushort_t* Hpb   = (ushort_t*)(base + alloc((size_t)N * HID * 2));
    ushort_t* posb  = (ushort_t*)(base + alloc((size_t)N * HID * 2));
    ushort_t* negb  = (ushort_t*)(base + alloc((size_t)N * HID * 2));
    int*      csr   = (int*)    (base + alloc((size_t)E * 4));
    int*      cnt   = (int*)    (base + alloc((size_t)N * 4));
    float*    smallb= (float*)  (base + alloc(130 * 4));
    int*      rowptr= (int*)    (base + alloc(((size_t)N + 1) * 4));
    int*      cursor= (int*)    (base + alloc((size_t)N * 4));
    float*    dinv  = (float*)  (base + alloc((size_t)N * 4));
    int*      partial=(int*)    (base + alloc(128 * 4));
    float* sumvec = smallb;
    float* lossAcc= smallb + 128;

    int B = (N + 1023) / 1024;            // 98
    int nbE = (E + 255) / 256;
    int nbG = (N + 63) / 64;              // covers N for cnt zeroing
    int nbP = (N * 32 + 255) / 256;       // covers N*32 u32 copies (>= E too)

    k_gemm<<<nbG, 256, 0, stream>>>(x, W_gcn, Hb, cnt, smallb, N);
    k_count_perm<<<nbP, 256, 0, stream>>>(dst, cnt, E, perm, Hb, Hpb, N);
    k_scan1<<<B, 256, 0, stream>>>(cnt, partial, N);
    k_scan3<<<B, 256, 0, stream>>>(cnt, partial, rowptr, cursor, dinv, N, E);
    k_fill<<<nbE, 256, 0, stream>>>(src, dst, cursor, csr, E);
    k_gather<<<2048, 256, 0, stream>>>(Hb, Hpb, rowptr, csr, dinv,
                                       b_gcn, prelu_a, posb, negb, sumvec, N);
    k_loss<<<512, 256, 0, stream>>>(posb, negb, sumvec, W_disc, lossAcc, N);
    k_final<<<1, 1, 0, stream>>>(lossAcc, (float*)d_out, N);
}

// Round 10
// 305.175 us; speedup vs baseline: 1.3602x; 1.3602x over previous
//
#include <hip/hip_runtime.h>

#define HID 64
#define INDIM 128
#define NBUCK 256          // bucket = dst >> 9  (512 nodes/bucket)
#define EBUF_PER 10240     // fixed ebuf region per bucket (avg fill 8192)
#define CHUNK 4096         // edges per binA block

typedef unsigned short ushort_t;
typedef unsigned int uint_t;

__device__ __forceinline__ float softplusf(float x) {
    return fmaxf(x, 0.f) + log1pf(expf(-fabsf(x)));
}
__device__ __forceinline__ ushort_t f2bf(float f) {
    union { float f; uint_t i; } c; c.f = f;
    uint_t u = c.i;
    u += 0x7FFFu + ((u >> 16) & 1u);   // round to nearest even
    return (ushort_t)(u >> 16);
}
__device__ __forceinline__ float lo_bf(uint_t u) {
    union { uint_t i; float f; } c; c.i = u << 16; return c.f;
}
__device__ __forceinline__ float hi_bf(uint_t u) {
    union { uint_t i; float f; } c; c.i = u & 0xFFFF0000u; return c.f;
}

// ------ H = x @ W (bf16 out) + zero cnt/smallb + init bcur ----------------
__global__ __launch_bounds__(256) void k_gemm(const float* __restrict__ x,
                                              const float* __restrict__ W,
                                              ushort_t* __restrict__ Hb,
                                              int* __restrict__ cnt,
                                              float* __restrict__ smallb,
                                              int* __restrict__ bcur, int N) {
    __shared__ float Xs[64 * 132];
    __shared__ float Ws[128 * 64];
    int tid = threadIdx.x;
    int row0 = blockIdx.x * 64;

    if (tid < 64 && row0 + tid < N) cnt[row0 + tid] = 0;
    if (blockIdx.x == 0 && tid < 130) smallb[tid] = 0.f;
    if (blockIdx.x == 1 && tid < NBUCK) bcur[tid] = tid * EBUF_PER;

    const float4* W4 = (const float4*)W;
    float4* Ws4 = (float4*)Ws;
#pragma unroll
    for (int i = 0; i < 8; i++) Ws4[tid + 256 * i] = W4[tid + 256 * i];

#pragma unroll
    for (int i = 0; i < 8; i++) {
        int j = tid + 256 * i;
        int r = j >> 5, c4 = j & 31;
        int row = row0 + r;
        float4 v = make_float4(0.f, 0.f, 0.f, 0.f);
        if (row < N) v = *(const float4*)(x + row * INDIM + c4 * 4);
        *(float4*)(&Xs[r * 132 + c4 * 4]) = v;
    }
    __syncthreads();

    int tx = tid & 15;
    int ty = tid >> 4;
    float acc[4][4] = {};
    const float* xa = &Xs[(ty * 4) * 132];
#pragma unroll 4
    for (int k = 0; k < 128; k++) {
        float4 b = *(const float4*)(&Ws[k * 64 + tx * 4]);
#pragma unroll
        for (int i = 0; i < 4; i++) {
            float a = xa[i * 132 + k];
            acc[i][0] = fmaf(a, b.x, acc[i][0]);
            acc[i][1] = fmaf(a, b.y, acc[i][1]);
            acc[i][2] = fmaf(a, b.z, acc[i][2]);
            acc[i][3] = fmaf(a, b.w, acc[i][3]);
        }
    }
#pragma unroll
    for (int i = 0; i < 4; i++) {
        int row = row0 + ty * 4 + i;
        if (row < N) {
            ushort4 o;
            o.x = f2bf(acc[i][0]); o.y = f2bf(acc[i][1]);
            o.z = f2bf(acc[i][2]); o.w = f2bf(acc[i][3]);
            *(ushort4*)(&Hb[(size_t)row * HID + tx * 4]) = o;
        }
    }
}

// ------ pass A: histogram + LDS-binned bucket scatter into ebuf ------------
__global__ __launch_bounds__(256) void k_binA(const int* __restrict__ src,
                                              const int* __restrict__ dst,
                                              int* __restrict__ cnt,
                                              int* __restrict__ bcur,
                                              int2* __restrict__ ebuf, int E) {
    __shared__ int lcnt[NBUCK];
    __shared__ int binStart[NBUCK];
    __shared__ int lofs[NBUCK];
    __shared__ int gofs[NBUCK];
    __shared__ int scan[NBUCK];
    __shared__ int2 stage[CHUNK];
    int tid = threadIdx.x;
    int base = blockIdx.x * CHUNK;

    lcnt[tid] = 0;
    __syncthreads();

    int sv[16], dv[16];
#pragma unroll
    for (int i = 0; i < 16; i++) {
        int e = base + i * 256 + tid;
        if (e < E) { sv[i] = src[e]; dv[i] = dst[e]; }
        else dv[i] = -1;
    }
#pragma unroll
    for (int i = 0; i < 16; i++) {
        if (dv[i] >= 0) {
            atomicAdd(&lcnt[dv[i] >> 9], 1);
            atomicAdd(&cnt[dv[i]], 1);          // fused global histogram
        }
    }
    __syncthreads();

    // exclusive scan of lcnt -> binStart
    scan[tid] = lcnt[tid];
    __syncthreads();
    for (int off = 1; off < NBUCK; off <<= 1) {
        int v = (tid >= off) ? scan[tid - off] : 0;
        __syncthreads();
        scan[tid] += v;
        __syncthreads();
    }
    binStart[tid] = scan[tid] - lcnt[tid];
    lofs[tid] = binStart[tid];
    __syncthreads();

    // place into LDS bins
#pragma unroll
    for (int i = 0; i < 16; i++) {
        if (dv[i] >= 0) {
            int b = dv[i] >> 9;
            int p = atomicAdd(&lofs[b], 1);
            stage[p] = make_int2(sv[i], dv[i]);
        }
    }
    __syncthreads();

    // reserve global runs
    if (lcnt[tid] > 0) gofs[tid] = atomicAdd(&bcur[tid], lcnt[tid]);
    __syncthreads();

    // copy bins out (runs are contiguous in ebuf)
    int total = (base + CHUNK <= E) ? CHUNK : (E > base ? E - base : 0);
    for (int idx = tid; idx < total; idx += 256) {
        int2 v = stage[idx];
        int b = v.y >> 9;
        ebuf[gofs[b] + (idx - binStart[b])] = v;
    }
}

// ---------------- scan stage 1: per-1024-chunk sums ------------------------
__global__ __launch_bounds__(256) void k_scan1(const int* __restrict__ cnt,
                                               int* __restrict__ partial, int N) {
    __shared__ int red[256];
    int base = blockIdx.x * 1024;
    int s = 0;
    for (int i = threadIdx.x; i < 1024; i += 256) {
        int idx = base + i;
        if (idx < N) s += cnt[idx];
    }
    red[threadIdx.x] = s;
    __syncthreads();
    for (int off = 128; off; off >>= 1) {
        if (threadIdx.x < off) red[threadIdx.x] += red[threadIdx.x + off];
        __syncthreads();
    }
    if (threadIdx.x == 0) partial[blockIdx.x] = red[0];
}

// ------ scan stage 2: redundant in-LDS scan of partials + per-chunk rowptr -
__global__ __launch_bounds__(256) void k_scan3(const int* __restrict__ cnt,
                                               const int* __restrict__ partial,
                                               int* __restrict__ rowptr,
                                               float* __restrict__ dinv,
                                               int N, int E) {
    __shared__ int sp[128];
    __shared__ int sc[256];
    int tid = threadIdx.x;
    int B98 = (N + 1023) >> 10;
    if (tid < 128) sp[tid] = (tid < B98) ? partial[tid] : 0;
    __syncthreads();
    for (int off = 1; off < 128; off <<= 1) {
        int v = (tid < 128 && tid >= off) ? sp[tid - off] : 0;
        __syncthreads();
        if (tid < 128) sp[tid] += v;
        __syncthreads();
    }
    int chunkEx = sp[blockIdx.x] - partial[blockIdx.x];
    __syncthreads();

    int base = blockIdx.x << 10;
    int i0 = base + tid * 4;
    int v0 = 0, v1 = 0, v2 = 0, v3 = 0;
    if (i0 + 3 < N) {
        int4 c = *(const int4*)(cnt + i0);
        v0 = c.x; v1 = c.y; v2 = c.z; v3 = c.w;
    } else {
        if (i0 < N)     v0 = cnt[i0];
        if (i0 + 1 < N) v1 = cnt[i0 + 1];
        if (i0 + 2 < N) v2 = cnt[i0 + 2];
        if (i0 + 3 < N) v3 = cnt[i0 + 3];
    }
    int s = v0 + v1 + v2 + v3;
    sc[tid] = s;
    __syncthreads();
    for (int off = 1; off < 256; off <<= 1) {
        int t = (tid >= off) ? sc[tid - off] : 0;
        __syncthreads();
        sc[tid] += t;
        __syncthreads();
    }
    int ex = sc[tid] - s + chunkEx;
    int r0 = ex, r1 = ex + v0, r2 = ex + v0 + v1, r3 = ex + v0 + v1 + v2;
    if (i0 < N)     { rowptr[i0]   = r0; dinv[i0]   = rsqrtf((float)(v0 + 1)); }
    if (i0 + 1 < N) { rowptr[i0+1] = r1; dinv[i0+1] = rsqrtf((float)(v1 + 1)); }
    if (i0 + 2 < N) { rowptr[i0+2] = r2; dinv[i0+2] = rsqrtf((float)(v2 + 1)); }
    if (i0 + 3 < N) { rowptr[i0+3] = r3; dinv[i0+3] = rsqrtf((float)(v3 + 1)); }
    if (blockIdx.x == 0 && tid == 0) rowptr[N] = E;
}

// ------ pass B: per-bucket exact placement with LDS cursor -----------------
// block b owns nodes [b*512, b*512+512) and csr region [rowptr[b*512], ...)
__global__ __launch_bounds__(256) void k_binB(const int2* __restrict__ ebuf,
                                              const int* __restrict__ bcur,
                                              const int* __restrict__ rowptr,
                                              const int* __restrict__ perm,
                                              const float* __restrict__ dinv,
                                              int2* __restrict__ csrS,
                                              float* __restrict__ csrN, int N) {
    __shared__ int lcur[512];
    int tid = threadIdx.x;
    int b = blockIdx.x;
    int nodeBase = b << 9;
    for (int i = tid; i < 512; i += 256) {
        int n = nodeBase + i;
        lcur[i] = (n < N) ? rowptr[n] : 0;
    }
    __syncthreads();

    int start = b * EBUF_PER;
    int end = bcur[b];
    for (int idx = start + tid; idx < end; idx += 256) {
        int2 v = ebuf[idx];
        int s = v.x, d = v.y;
        int j = atomicAdd(&lcur[d & 511], 1);
        csrS[j] = make_int2(s, perm[s]);
        csrN[j] = dinv[s] * dinv[d];
    }
}

// ------ fused pull-gather (R8 form): prefetched csr, precomputed norms -----
__global__ __launch_bounds__(256) void k_gather(const ushort_t* __restrict__ Hb,
                                                const int* __restrict__ rowptr,
                                                const int2* __restrict__ csrS,
                                                const float* __restrict__ csrN,
                                                const int* __restrict__ perm,
                                                const float* __restrict__ dinv,
                                                const float* __restrict__ b,
                                                const float* __restrict__ a,
                                                ushort_t* __restrict__ posb,
                                                ushort_t* __restrict__ negb,
                                                float* __restrict__ sumvec, int N) {
    int tid = threadIdx.x;
    int lane = tid & 63;
    int half = lane >> 5;
    int sub = lane & 31;
    int wid = (blockIdx.x * 256 + tid) >> 6;
    int nw = gridDim.x * 4;
    const uint_t* H32 = (const uint_t*)Hb;     // row stride = 32 u32
    float2 b2 = ((const float2*)b)[sub];
    float2 a2 = ((const float2*)a)[sub];
    float sum0 = 0.f, sum1 = 0.f;

    for (int n = wid; n < N; n += nw) {
        float dv = dinv[n];
        float w2 = dv * dv;
        int beg = rowptr[n], end = rowptr[n + 1];
        float accP0 = 0.f, accP1 = 0.f, accN0 = 0.f, accN1 = 0.f;
        int eA = beg + half, eB = beg + 2 + half;
        bool vA = eA < end, vB = eB < end;
        int2 spA = vA ? csrS[eA] : make_int2(0, 0);
        int2 spB = vB ? csrS[eB] : make_int2(0, 0);
        float nmA = vA ? csrN[eA] : 0.f;
        float nmB = vB ? csrN[eB] : 0.f;
        for (int j = beg; j < end; j += 4) {
            int fA = j + 4 + half, fB = j + 6 + half;
            bool wA = fA < end, wB = fB < end;
            int2 npA = wA ? csrS[fA] : make_int2(0, 0);
            int2 npB = wB ? csrS[fB] : make_int2(0, 0);
            float nnA = wA ? csrN[fA] : 0.f;
            float nnB = wB ? csrN[fB] : 0.f;
            uint_t upA = H32[spA.x * 32 + sub];
            uint_t unA = H32[spA.y * 32 + sub];
            uint_t upB = H32[spB.x * 32 + sub];
            uint_t unB = H32[spB.y * 32 + sub];
            accP0 = fmaf(lo_bf(upA), nmA, accP0);
            accP1 = fmaf(hi_bf(upA), nmA, accP1);
            accN0 = fmaf(lo_bf(unA), nmA, accN0);
            accN1 = fmaf(hi_bf(unA), nmA, accN1);
            accP0 = fmaf(lo_bf(upB), nmB, accP0);
            accP1 = fmaf(hi_bf(upB), nmB, accP1);
            accN0 = fmaf(lo_bf(unB), nmB, accN0);
            accN1 = fmaf(hi_bf(unB), nmB, accN1);
            spA = npA; spB = npB; nmA = nnA; nmB = nnB;
        }
        accP0 += __shfl_xor(accP0, 32);
        accP1 += __shfl_xor(accP1, 32);
        accN0 += __shfl_xor(accN0, 32);
        accN1 += __shfl_xor(accN1, 32);
        int selfrow = half ? perm[n] : n;
        uint_t us = H32[selfrow * 32 + sub];
        float e0 = half ? accN0 : accP0;
        float e1 = half ? accN1 : accP1;
        float v0 = fmaf(lo_bf(us), w2, e0) + b2.x;
        float v1 = fmaf(hi_bf(us), w2, e1) + b2.y;
        v0 = v0 > 0.f ? v0 : v0 * a2.x;
        v1 = v1 > 0.f ? v1 : v1 * a2.y;
        uint_t packed = ((uint_t)f2bf(v1) << 16) | (uint_t)f2bf(v0);
        uint_t* outp = (uint_t*)(half ? negb : posb);
        outp[n * 32 + sub] = packed;
        if (!half) { sum0 += v0; sum1 += v1; }
    }

    __shared__ float red[4][64];
    int w = tid >> 6;
    if (!half) { red[w][2 * sub] = sum0; red[w][2 * sub + 1] = sum1; }
    __syncthreads();
    if (tid < 64) {
        float s = red[0][tid] + red[1][tid] + red[2][tid] + red[3][tid];
        atomicAdd(&sumvec[tid], s);
    }
}

// ------ loss with fused discriminator (svec computed per-block) ------------
__global__ __launch_bounds__(256) void k_loss(const ushort_t* __restrict__ posb,
                                              const ushort_t* __restrict__ negb,
                                              const float* __restrict__ sumvec,
                                              const float* __restrict__ Wd,
                                              float* __restrict__ lossAcc, int N) {
    __shared__ float summ[64];
    __shared__ float svecS[64];
    __shared__ float redL[8];
    int tid = threadIdx.x;
    if (tid < 64) summ[tid] = 1.f / (1.f + expf(-sumvec[tid] / (float)N));
    __syncthreads();
    if (tid < 64) {
        float s = 0.f;
#pragma unroll
        for (int j = 0; j < 64; j++) s += Wd[tid * 64 + j] * summ[j];
        svecS[tid] = s;
    }
    __syncthreads();

    int lane = tid & 63;
    int half = lane >> 5;
    int sub = lane & 31;
    int w = tid >> 6;
    float s0 = svecS[2 * sub], s1 = svecS[2 * sub + 1];
    const uint_t* P32 = (const uint_t*)(half ? negb : posb);
    float l = 0.f;
    int wid = (blockIdx.x * 256 + tid) >> 6;
    int nw = gridDim.x * 4;
    for (int n = wid; n < N; n += nw) {
        uint_t u = P32[n * 32 + sub];
        float p = lo_bf(u) * s0 + hi_bf(u) * s1;
        p += __shfl_xor(p, 1);
        p += __shfl_xor(p, 2);
        p += __shfl_xor(p, 4);
        p += __shfl_xor(p, 8);
        p += __shfl_xor(p, 16);
        if (sub == 0) l += half ? softplusf(p) : softplusf(-p);
    }
    if (sub == 0) redL[w * 2 + half] = l;
    __syncthreads();
    if (tid == 0) {
        float t = 0.f;
#pragma unroll
        for (int i = 0; i < 8; i++) t += redL[i];
        atomicAdd(&lossAcc[0], t);
    }
}

// ---------------- final scalar ---------------------------------------------
__global__ void k_final(const float* __restrict__ lossAcc, float* __restrict__ out, int N) {
    out[0] = lossAcc[0] / (float)N;
}

extern "C" void kernel_launch(void* const* d_in, const int* in_sizes, int n_in,
                              void* d_out, int out_size, void* d_ws, size_t ws_size,
                              hipStream_t stream) {
    const float* x      = (const float*)d_in[0];
    const float* W_gcn  = (const float*)d_in[1];
    const float* b_gcn  = (const float*)d_in[2];
    const float* prelu_a= (const float*)d_in[3];
    const float* W_disc = (const float*)d_in[4];
    const int*   eidx   = (const int*)d_in[5];
    const int*   perm   = (const int*)d_in[6];

    int N = in_sizes[0] / INDIM;      // 100000
    int E = in_sizes[5] / 2;          // 1600000
    const int* src = eidx;
    const int* dst = eidx + E;

    char* base = (char*)d_ws;
    size_t off = 0;
    auto alloc = [&](size_t bytes) { size_t o = off; off = (off + bytes + 255) & ~(size_t)255; return o; };
    ushort_t* Hb    = (ushort_t*)(base + alloc((size_t)N * HID * 2));
    ushort_t* posb  = (ushort_t*)(base + alloc((size_t)N * HID * 2));
    ushort_t* negb  = (ushort_t*)(base + alloc((size_t)N * HID * 2));
    int2*     csrS  = (int2*)   (base + alloc((size_t)E * 8));
    float*    csrN  = (float*)  (base + alloc((size_t)E * 4));
    int2*     ebuf  = (int2*)   (base + alloc((size_t)NBUCK * EBUF_PER * 8));
    int*      cnt   = (int*)    (base + alloc((size_t)N * 4));
    float*    smallb= (float*)  (base + alloc(130 * 4));
    int*      rowptr= (int*)    (base + alloc(((size_t)N + 1) * 4));
    float*    dinv  = (float*)  (base + alloc((size_t)N * 4));
    int*      partial=(int*)    (base + alloc(128 * 4));
    int*      bcur  = (int*)    (base + alloc(NBUCK * 4));
    float* sumvec = smallb;
    float* lossAcc= smallb + 128;

    int B = (N + 1023) / 1024;            // 98
    int nbG = (N + 63) / 64;              // covers N for cnt zeroing
    int nbA = (E + CHUNK - 1) / CHUNK;    // 391
    int nbB = (N + 511) / 512;            // 196

    k_gemm<<<nbG, 256, 0, stream>>>(x, W_gcn, Hb, cnt, smallb, bcur, N);
    k_binA<<<nbA, 256, 0, stream>>>(src, dst, cnt, bcur, ebuf, E);
    k_scan1<<<B, 256, 0, stream>>>(cnt, partial, N);
    k_scan3<<<B, 256, 0, stream>>>(cnt, partial, rowptr, dinv, N, E);
    k_binB<<<nbB, 256, 0, stream>>>(ebuf, bcur, rowptr, perm, dinv, csrS, csrN, N);
    k_gather<<<2048, 256, 0, stream>>>(Hb, rowptr, csrS, csrN, perm, dinv,
                                       b_gcn, prelu_a, posb, negb, sumvec, N);
    k_loss<<<512, 256, 0, stream>>>(posb, negb, sumvec, W_disc, lossAcc, N);
    k_final<<<1, 1, 0, stream>>>(lossAcc, (float*)d_out, N);
}